// Round 19
// baseline (196.638 us; speedup 1.0000x reference)
//
#include <hip/hip_runtime.h>
#include <hip/hip_bf16.h>
#include <math.h>

#define NN 2048
#define NEG 0.2f
#define LOG2E 1.44269504f

typedef short bf16x8 __attribute__((ext_vector_type(8)));
typedef float f32x16 __attribute__((ext_vector_type(16)));

__device__ __forceinline__ float dot4(float4 a, float4 b) {
  return a.x * b.x + a.y * b.y + a.z * b.z + a.w * b.w;
}

__device__ __forceinline__ unsigned short bfbits(float f) {
  union { __hip_bfloat16 b; unsigned short u; } c;
  c.b = __float2bfloat16(f);
  return c.u;
}

// ---------------------------------------------------------------------------
// K12: grid 2056 (8 blocks/CU). even p<2048: 16-row GEMM tile (p>>1);
// odd p<2048: 16-row adjacency pack; p>=2048: GGE MLP.
// Finer tiles double resident waves -> latency hiding via TLP (k3 r2 lesson).
// ---------------------------------------------------------------------------
__global__ __launch_bounds__(256) void k12_fused(const float* __restrict__ bioA,
                                                 const float* __restrict__ bioB,
                                                 const float* __restrict__ initW,
                                                 const float* __restrict__ initb,
                                                 const float* __restrict__ projW,
                                                 const float* __restrict__ attw,
                                                 const float* __restrict__ a_in,
                                                 const float* __restrict__ b_in,
                                                 const float* __restrict__ ggeW1,
                                                 const float* __restrict__ ggeb1,
                                                 const float* __restrict__ ggeW2,
                                                 const float* __restrict__ ggeb2,
                                                 const int* __restrict__ adjA,
                                                 const int* __restrict__ adjB,
                                                 unsigned int* __restrict__ adjP,
                                                 float* __restrict__ xout,
                                                 unsigned short* __restrict__ xhT2,
                                                 float* __restrict__ s1,
                                                 float* __restrict__ s2,
                                                 float* __restrict__ hvbuf,
                                                 float* __restrict__ e) {
  __shared__ float As[32][20];
  __shared__ float Ws[32][132];
  const int t = threadIdx.x;
  const int wave = t >> 6, lane = t & 63;
  const int p = (int)blockIdx.x;

  if (p >= 2048) {
    // ----- GGE branch, 8 blocks -----
    float* inL = (float*)Ws;
    float* h1L = ((float*)Ws) + 512;
    const int bb2 = p - 2048;
    const int g = bb2 >> 2, b = bb2 & 3;
    const int gb2 = g * 4 + b;
    const float* inp = (g ? b_in : a_in) + b * 512;
    if (t < 128) *(float4*)&inL[t * 4] = *(const float4*)&inp[t * 4];
    __syncthreads();
    for (int q = 0; q < 16; ++q) {
      const int o0 = q * 8 + wave * 2;
      const float* w0 = &ggeW1[o0 * 512 + lane * 8];
      const float* w1 = &ggeW1[(o0 + 1) * 512 + lane * 8];
      const float4 i0v = *(const float4*)&inL[lane * 8];
      const float4 i1v = *(const float4*)&inL[lane * 8 + 4];
      float s0 = dot4(*(const float4*)&w0[0], i0v) + dot4(*(const float4*)&w0[4], i1v);
      float s1v = dot4(*(const float4*)&w1[0], i0v) + dot4(*(const float4*)&w1[4], i1v);
#pragma unroll
      for (int s = 1; s < 64; s <<= 1) { s0 += __shfl_xor(s0, s); s1v += __shfl_xor(s1v, s); }
      if (lane == 0) {
        h1L[o0] = fmaxf(s0 + ggeb1[o0], 0.f);
        h1L[o0 + 1] = fmaxf(s1v + ggeb1[o0 + 1], 0.f);
      }
    }
    __syncthreads();
    for (int q = 0; q < 16; ++q) {
      const int o0 = q * 8 + wave * 2;
      const float2 w0 = *(const float2*)&ggeW2[o0 * 128 + lane * 2];
      const float2 w1 = *(const float2*)&ggeW2[(o0 + 1) * 128 + lane * 2];
      const float2 hvv = *(const float2*)&h1L[lane * 2];
      float s0 = w0.x * hvv.x + w0.y * hvv.y;
      float s1v = w1.x * hvv.x + w1.y * hvv.y;
#pragma unroll
      for (int s = 1; s < 64; s <<= 1) { s0 += __shfl_xor(s0, s); s1v += __shfl_xor(s1v, s); }
      if (lane == 0) {
        const float v0 = fmaxf(s0 + ggeb2[o0], 0.f);
        const float v1 = fmaxf(s1v + ggeb2[o0 + 1], 0.f);
        hvbuf[gb2 * 128 + o0] = v0;
        hvbuf[gb2 * 128 + o0 + 1] = v1;
        e[gb2 * 256 + o0] = v0;
        e[gb2 * 256 + o0 + 1] = v1;
      }
    }
    return;
  }

  if (p & 1) {
    // ----- adjacency pack branch, 1024 blocks (16 rows each) -----
    const int pb = p >> 1;               // 0..1023
    const int chunk = pb >> 1;           // cidx 0..511
    const int half = pb & 1;
    const int g = chunk >> 8, b = (chunk >> 6) & 3;
    const int i0 = (chunk & 63) * 32 + half * 16;
    const int* adj = (g ? adjB : adjA) + (b * NN + i0) * NN;
    unsigned int* dst = adjP + chunk * 2048 + half * 1024;
#pragma unroll
    for (int r4 = 0; r4 < 4; ++r4) {
      const int r = wave * 4 + r4;
      const int* arow = adj + r * NN;
      int av[32];
#pragma unroll
      for (int w = 0; w < 32; ++w)
        av[w] = __builtin_nontemporal_load(&arow[w * 64 + lane]);
#pragma unroll
      for (int w = 0; w < 32; ++w) {
        const unsigned long long mm = __ballot(av[w] > 0);
        if (lane < 2) dst[r * 64 + 2 * w + lane] = (unsigned int)(mm >> (32 * lane));
      }
    }
    return;
  }

  // ----- GEMM branch, 1024 blocks (16-row tiles, register-pipelined) -----
  const int m0 = (p >> 1) * 16;
  const float* A = (m0 < 8192) ? bioA : bioB;
  const int arow0 = (m0 < 8192) ? m0 : (m0 - 8192);
  const int og = t & 31, ig = t >> 5;      // ig 0..7 -> rows ig*2, ig*2+1
  const int rA = t >> 3, kqA = t & 7;      // stagers: t<128 -> rA 0..15
  const int oW0 = t >> 3;                  // W staging: o = u*32 + t>>3

  float acc[2][4] = {};
  float4 nA = {0.f, 0.f, 0.f, 0.f}, nW0, nW1, nW2, nW3;
  if (t < 128) nA = *(const float4*)&A[(arow0 + rA) * 256 + kqA * 4];
  nW0 = *(const float4*)&initW[(0 * 32 + oW0) * 256 + kqA * 4];
  nW1 = *(const float4*)&initW[(1 * 32 + oW0) * 256 + kqA * 4];
  nW2 = *(const float4*)&initW[(2 * 32 + oW0) * 256 + kqA * 4];
  nW3 = *(const float4*)&initW[(3 * 32 + oW0) * 256 + kqA * 4];
  for (int kt = 0; kt < 256; kt += 32) {
    __syncthreads();
    if (t < 128) {
      As[kqA * 4 + 0][rA] = nA.x; As[kqA * 4 + 1][rA] = nA.y;
      As[kqA * 4 + 2][rA] = nA.z; As[kqA * 4 + 3][rA] = nA.w;
    }
    Ws[kqA * 4 + 0][0 * 32 + oW0] = nW0.x; Ws[kqA * 4 + 1][0 * 32 + oW0] = nW0.y;
    Ws[kqA * 4 + 2][0 * 32 + oW0] = nW0.z; Ws[kqA * 4 + 3][0 * 32 + oW0] = nW0.w;
    Ws[kqA * 4 + 0][1 * 32 + oW0] = nW1.x; Ws[kqA * 4 + 1][1 * 32 + oW0] = nW1.y;
    Ws[kqA * 4 + 2][1 * 32 + oW0] = nW1.z; Ws[kqA * 4 + 3][1 * 32 + oW0] = nW1.w;
    Ws[kqA * 4 + 0][2 * 32 + oW0] = nW2.x; Ws[kqA * 4 + 1][2 * 32 + oW0] = nW2.y;
    Ws[kqA * 4 + 2][2 * 32 + oW0] = nW2.z; Ws[kqA * 4 + 3][2 * 32 + oW0] = nW2.w;
    Ws[kqA * 4 + 0][3 * 32 + oW0] = nW3.x; Ws[kqA * 4 + 1][3 * 32 + oW0] = nW3.y;
    Ws[kqA * 4 + 2][3 * 32 + oW0] = nW3.z; Ws[kqA * 4 + 3][3 * 32 + oW0] = nW3.w;
    __syncthreads();
    if (kt < 224) {
      const int kn = kt + 32;
      if (t < 128) nA = *(const float4*)&A[(arow0 + rA) * 256 + kn + kqA * 4];
      nW0 = *(const float4*)&initW[(0 * 32 + oW0) * 256 + kn + kqA * 4];
      nW1 = *(const float4*)&initW[(1 * 32 + oW0) * 256 + kn + kqA * 4];
      nW2 = *(const float4*)&initW[(2 * 32 + oW0) * 256 + kn + kqA * 4];
      nW3 = *(const float4*)&initW[(3 * 32 + oW0) * 256 + kn + kqA * 4];
    }
    __builtin_amdgcn_sched_barrier(0);
#pragma unroll
    for (int kk = 0; kk < 32; ++kk) {
      const float2 a2 = *(const float2*)&As[kk][ig * 2];
      const float4 w4 = *(const float4*)&Ws[kk][og * 4];
      const float wv[4] = {w4.x, w4.y, w4.z, w4.w};
#pragma unroll
      for (int jj = 0; jj < 4; ++jj) {
        acc[0][jj] += a2.x * wv[jj];
        acc[1][jj] += a2.y * wv[jj];
      }
    }
  }
  {
    const float4 b4 = *(const float4*)&initb[og * 4];
    const float bj[4] = {b4.x, b4.y, b4.z, b4.w};
#pragma unroll
    for (int ii = 0; ii < 2; ++ii) {
      const int row = m0 + ig * 2 + ii;
      float4 o4;
      o4.x = acc[ii][0] + bj[0]; o4.y = acc[ii][1] + bj[1];
      o4.z = acc[ii][2] + bj[2]; o4.w = acc[ii][3] + bj[3];
      *(float4*)&xout[row * 128 + og * 4] = o4;
    }
  }

  // ----- phase 2: proj (K=128; x re-staged from global, W pipelined) -----
  float acc2[2][4] = {};
  float4 nX = {0.f, 0.f, 0.f, 0.f};
  if (t < 128) nX = *(const float4*)&xout[(m0 + rA) * 128 + kqA * 4];
  nW0 = *(const float4*)&projW[(0 * 32 + oW0) * 128 + kqA * 4];
  nW1 = *(const float4*)&projW[(1 * 32 + oW0) * 128 + kqA * 4];
  nW2 = *(const float4*)&projW[(2 * 32 + oW0) * 128 + kqA * 4];
  nW3 = *(const float4*)&projW[(3 * 32 + oW0) * 128 + kqA * 4];
  for (int kt = 0; kt < 128; kt += 32) {
    __syncthreads();
    if (t < 128) {
      As[kqA * 4 + 0][rA] = nX.x; As[kqA * 4 + 1][rA] = nX.y;
      As[kqA * 4 + 2][rA] = nX.z; As[kqA * 4 + 3][rA] = nX.w;
    }
    Ws[kqA * 4 + 0][0 * 32 + oW0] = nW0.x; Ws[kqA * 4 + 1][0 * 32 + oW0] = nW0.y;
    Ws[kqA * 4 + 2][0 * 32 + oW0] = nW0.z; Ws[kqA * 4 + 3][0 * 32 + oW0] = nW0.w;
    Ws[kqA * 4 + 0][1 * 32 + oW0] = nW1.x; Ws[kqA * 4 + 1][1 * 32 + oW0] = nW1.y;
    Ws[kqA * 4 + 2][1 * 32 + oW0] = nW1.z; Ws[kqA * 4 + 3][1 * 32 + oW0] = nW1.w;
    Ws[kqA * 4 + 0][2 * 32 + oW0] = nW2.x; Ws[kqA * 4 + 1][2 * 32 + oW0] = nW2.y;
    Ws[kqA * 4 + 2][2 * 32 + oW0] = nW2.z; Ws[kqA * 4 + 3][2 * 32 + oW0] = nW2.w;
    Ws[kqA * 4 + 0][3 * 32 + oW0] = nW3.x; Ws[kqA * 4 + 1][3 * 32 + oW0] = nW3.y;
    Ws[kqA * 4 + 2][3 * 32 + oW0] = nW3.z; Ws[kqA * 4 + 3][3 * 32 + oW0] = nW3.w;
    __syncthreads();
    if (kt < 96) {
      const int kn = kt + 32;
      if (t < 128) nX = *(const float4*)&xout[(m0 + rA) * 128 + kn + kqA * 4];
      nW0 = *(const float4*)&projW[(0 * 32 + oW0) * 128 + kn + kqA * 4];
      nW1 = *(const float4*)&projW[(1 * 32 + oW0) * 128 + kn + kqA * 4];
      nW2 = *(const float4*)&projW[(2 * 32 + oW0) * 128 + kn + kqA * 4];
      nW3 = *(const float4*)&projW[(3 * 32 + oW0) * 128 + kn + kqA * 4];
    }
    __builtin_amdgcn_sched_barrier(0);
#pragma unroll
    for (int kk = 0; kk < 32; ++kk) {
      const float2 a2 = *(const float2*)&As[kk][ig * 2];
      const float4 w4 = *(const float4*)&Ws[kk][og * 4];
      const float wv[4] = {w4.x, w4.y, w4.z, w4.w};
#pragma unroll
      for (int jj = 0; jj < 4; ++jj) {
        acc2[0][jj] += a2.x * wv[jj];
        acc2[1][jj] += a2.y * wv[jj];
      }
    }
  }
  const int h = og >> 3;
  const int k4i = (og & 7) * 4;
  const int g = m0 >> 13;
  const int bb = (m0 >> 11) & 3;
  const int gb = g * 4 + bb;
  const int n0 = (m0 & 2047) + ig * 2;
  const float4 w1 = *(const float4*)&attw[h * 64 + k4i];
  const float4 w2 = *(const float4*)&attw[h * 64 + 32 + k4i];
  float p1[2], p2[2];
#pragma unroll
  for (int ii = 0; ii < 2; ++ii) {
    float4 v;
    v.x = acc2[ii][0]; v.y = acc2[ii][1]; v.z = acc2[ii][2]; v.w = acc2[ii][3];
    p1[ii] = dot4(v, w1);
    p2[ii] = dot4(v, w2);
  }
  {
    const int mtile = n0 >> 4, jslot = (n0 >> 3) & 1, j8 = n0 & 7;
    const int base2 = ((((gb * 4 + h) * 128 + mtile) * 2 + jslot) * 32) * 8 + j8;
#pragma unroll
    for (int jj = 0; jj < 4; ++jj) {
      const int kin = k4i + jj;
      ushort2 u;
      u.x = bfbits(acc2[0][jj]); u.y = bfbits(acc2[1][jj]);
      *(ushort2*)&xhT2[base2 + kin * 8] = u;
    }
  }
#pragma unroll
  for (int s = 1; s < 8; s <<= 1) {
#pragma unroll
    for (int ii = 0; ii < 2; ++ii) {
      p1[ii] += __shfl_xor(p1[ii], s);
      p2[ii] += __shfl_xor(p2[ii], s);
    }
  }
  if ((og & 7) == 0) {
#pragma unroll
    for (int ii = 0; ii < 2; ++ii) {
      s1[(gb * 4 + h) * NN + n0 + ii] = p1[ii];
      s2[(gb * 4 + h) * NN + n0 + ii] = p2[ii];
    }
  }
}

#define K3_SCORE_BODY(MM)                                                     \
    const int j0 = jlo + 16 * (MM) + jslot * 8;                               \
    const unsigned int wbits = adjL[i * 66 + ((jlo + 16 * (MM)) >> 5)];       \
    const unsigned int bits8 = wbits >> ((((MM) & 1) * 16) + jslot * 8);      \
    const float4 s2a = *(const float4*)&s2L[h * 2048 + j0];                   \
    const float4 s2b = *(const float4*)&s2L[h * 2048 + j0 + 4];               \
    const float sv[8] = {s2a.x, s2a.y, s2a.z, s2a.w,                          \
                         s2b.x, s2b.y, s2b.z, s2b.w};                         \
    union { bf16x8 v; unsigned short u[8]; } af;                              \
    float dsum = 0.f;                                                         \
    _Pragma("unroll")                                                         \
    for (int e = 0; e < 8; ++e) {                                             \
      float s = sc1v + sv[e];                                                 \
      s = fmaxf(s, NEG * s);                                                  \
      float pe = __builtin_amdgcn_exp2f(s);                                   \
      pe = ((bits8 >> e) & 1u) ? pe : 0.f;                                    \
      af.u[e] = bfbits(pe);                                                   \
      dsum += pe;                                                             \
    }                                                                         \
    den += dsum;

// ---------------------------------------------------------------------------
// K3: unchanged (packed adjacency prologue, 16-frag ring, chunk-softmax
// epilogue).
// ---------------------------------------------------------------------------
__global__ __launch_bounds__(512) void k3_attn(const unsigned short* __restrict__ xhT2,
                                               const float* __restrict__ s1w,
                                               const float* __restrict__ s2w,
                                               const unsigned int* __restrict__ adjP,
                                               const float* __restrict__ attb,
                                               const float* __restrict__ x,
                                               const float* __restrict__ hv,
                                               float* __restrict__ G,
                                               float* __restrict__ wsumC,
                                               float* __restrict__ mzC) {
  __shared__ __align__(16) unsigned char smem3[42240];
  unsigned int* adjL = (unsigned int*)smem3;
  float* s2L = (float*)(smem3 + 8448);
  float* denR = (float*)(smem3 + 41216);
  float* accR = (float*)smem3;
  float* lgW = (float*)(smem3 + 16640);   // [4][32]
  float* pL = (float*)(smem3 + 17280);    // [32]

  const int t = threadIdx.x;
  const int wave = t >> 6, lane = t & 63;
  const int p = (int)blockIdx.x;
  const int blk = (p & 7) * 64 + (p >> 3);
  const int g = blk >> 8, b = (blk >> 6) & 3;
  const int i0 = (blk & 63) * 32;
  const int gb = g * 4 + b;
  const int cidx = gb * 64 + (blk & 63);
  {
    const float* s2g = s2w + gb * 4 * NN;
#pragma unroll
    for (int u = 0; u < 4; ++u) {
      const int idx = u * 2048 + t * 4;
      float4 v = *(const float4*)&s2g[idx];
      v.x *= LOG2E; v.y *= LOG2E; v.z *= LOG2E; v.w *= LOG2E;
      *(float4*)&s2L[idx] = v;
    }
    const int q0 = t * 4;
    const int4 v = *(const int4*)&adjP[cidx * 2048 + q0];
    const int rr = q0 >> 6, ww = q0 & 63;
    adjL[rr * 66 + ww + 0] = (unsigned int)v.x;
    adjL[rr * 66 + ww + 1] = (unsigned int)v.y;
    adjL[rr * 66 + ww + 2] = (unsigned int)v.z;
    adjL[rr * 66 + ww + 3] = (unsigned int)v.w;
  }
  __syncthreads();

  const int h = wave & 3;
  const int jhalf = wave >> 2;
  const int jlo = jhalf * 1024;
  const int i = lane & 31;
  const int jslot = lane >> 5;
  const float sc1v = (s1w[(gb * 4 + h) * NN + i0 + i] + attb[h]) * LOG2E;
  const unsigned short* bbase = xhT2 + (gb * 4 + h) * 65536 + jhalf * 32768 + lane * 8;
  f32x16 acc = {0.f, 0.f, 0.f, 0.f, 0.f, 0.f, 0.f, 0.f,
                0.f, 0.f, 0.f, 0.f, 0.f, 0.f, 0.f, 0.f};
  float den = 0.f;

#define K3_CSTEP(RB, MM)                                                      \
  {                                                                           \
    K3_SCORE_BODY(MM)                                                         \
    acc = __builtin_amdgcn_mfma_f32_32x32x16_bf16(af.v, RB, acc, 0, 0, 0);    \
  }

  bf16x8 fa0 = *(const bf16x8*)&bbase[0 * 512];
  bf16x8 fa1 = *(const bf16x8*)&bbase[1 * 512];
  bf16x8 fa2 = *(const bf16x8*)&bbase[2 * 512];
  bf16x8 fa3 = *(const bf16x8*)&bbase[3 * 512];
  bf16x8 fb0 = *(const bf16x8*)&bbase[4 * 512];
  bf16x8 fb1 = *(const bf16x8*)&bbase[5 * 512];
  bf16x8 fb2 = *(const bf16x8*)&bbase[6 * 512];
  bf16x8 fb3 = *(const bf16x8*)&bbase[7 * 512];
  bf16x8 fc0 = *(const bf16x8*)&bbase[8 * 512];
  bf16x8 fc1 = *(const bf16x8*)&bbase[9 * 512];
  bf16x8 fc2 = *(const bf16x8*)&bbase[10 * 512];
  bf16x8 fc3 = *(const bf16x8*)&bbase[11 * 512];
  bf16x8 fd0 = *(const bf16x8*)&bbase[12 * 512];
  bf16x8 fd1 = *(const bf16x8*)&bbase[13 * 512];
  bf16x8 fd2 = *(const bf16x8*)&bbase[14 * 512];
  bf16x8 fd3 = *(const bf16x8*)&bbase[15 * 512];
  __builtin_amdgcn_sched_barrier(0);
  for (int mb = 0; mb < 64; mb += 16) {
    K3_CSTEP(fa0, mb + 0)
    K3_CSTEP(fa1, mb + 1)
    K3_CSTEP(fa2, mb + 2)
    K3_CSTEP(fa3, mb + 3)
    __builtin_amdgcn_sched_barrier(0);
    if (mb < 48) {
      fa0 = *(const bf16x8*)&bbase[(mb + 16) * 512];
      fa1 = *(const bf16x8*)&bbase[(mb + 17) * 512];
      fa2 = *(const bf16x8*)&bbase[(mb + 18) * 512];
      fa3 = *(const bf16x8*)&bbase[(mb + 19) * 512];
    }
    __builtin_amdgcn_sched_barrier(0);
    K3_CSTEP(fb0, mb + 4)
    K3_CSTEP(fb1, mb + 5)
    K3_CSTEP(fb2, mb + 6)
    K3_CSTEP(fb3, mb + 7)
    __builtin_amdgcn_sched_barrier(0);
    if (mb < 48) {
      fb0 = *(const bf16x8*)&bbase[(mb + 20) * 512];
      fb1 = *(const bf16x8*)&bbase[(mb + 21) * 512];
      fb2 = *(const bf16x8*)&bbase[(mb + 22) * 512];
      fb3 = *(const bf16x8*)&bbase[(mb + 23) * 512];
    }
    __builtin_amdgcn_sched_barrier(0);
    K3_CSTEP(fc0, mb + 8)
    K3_CSTEP(fc1, mb + 9)
    K3_CSTEP(fc2, mb + 10)
    K3_CSTEP(fc3, mb + 11)
    __builtin_amdgcn_sched_barrier(0);
    if (mb < 48) {
      fc0 = *(const bf16x8*)&bbase[(mb + 24) * 512];
      fc1 = *(const bf16x8*)&bbase[(mb + 25) * 512];
      fc2 = *(const bf16x8*)&bbase[(mb + 26) * 512];
      fc3 = *(const bf16x8*)&bbase[(mb + 27) * 512];
    }
    __builtin_amdgcn_sched_barrier(0);
    K3_CSTEP(fd0, mb + 12)
    K3_CSTEP(fd1, mb + 13)
    K3_CSTEP(fd2, mb + 14)
    K3_CSTEP(fd3, mb + 15)
    __builtin_amdgcn_sched_barrier(0);
    if (mb < 48) {
      fd0 = *(const bf16x8*)&bbase[(mb + 28) * 512];
      fd1 = *(const bf16x8*)&bbase[(mb + 29) * 512];
      fd2 = *(const bf16x8*)&bbase[(mb + 30) * 512];
      fd3 = *(const bf16x8*)&bbase[(mb + 31) * 512];
    }
    __builtin_amdgcn_sched_barrier(0);
  }
#undef K3_CSTEP

  den += __shfl_xor(den, 32);
  if (lane < 32) denR[(h * 2 + jhalf) * 32 + lane] = den;
  __syncthreads();
  if (jhalf == 1) {
#pragma unroll
    for (int r = 0; r < 16; ++r) accR[(h * 16 + r) * 65 + lane] = acc[r];
  }
  __syncthreads();
  const float hvv = hv[gb * 128 + h * 32 + i];
  if (jhalf == 0) {
#pragma unroll
    for (int r = 0; r < 16; ++r) {
      const int row = (r & 3) + 8 * (r >> 2) + 4 * jslot;
      const float dinv = 1.f / (denR[(h * 2 + 0) * 32 + row] + denR[(h * 2 + 1) * 32 + row]);
      const int off = (gb * NN + i0 + row) * 128 + h * 32 + i;
      const float av2 = acc[r] + accR[(h * 16 + r) * 65 + lane];
      const float gval = fmaxf(av2 * dinv, 0.f) + x[off];
      G[off] = gval;
      float c = gval * hvv;
      c += __shfl_xor(c, 1); c += __shfl_xor(c, 2); c += __shfl_xor(c, 4);
      c += __shfl_xor(c, 8); c += __shfl_xor(c, 16);
      if (i == 0) lgW[h * 32 + row] = c;
    }
  }
  __syncthreads();
  if (t < 32) {
    float lg = lgW[t] + lgW[32 + t] + lgW[64 + t] + lgW[96 + t];
    float m = lg;
    m = fmaxf(m, __shfl_xor(m, 1)); m = fmaxf(m, __shfl_xor(m, 2));
    m = fmaxf(m, __shfl_xor(m, 4)); m = fmaxf(m, __shfl_xor(m, 8));
    m = fmaxf(m, __shfl_xor(m, 16));
    const float pv = __expf(lg - m);
    float z = pv;
    z += __shfl_xor(z, 1); z += __shfl_xor(z, 2); z += __shfl_xor(z, 4);
    z += __shfl_xor(z, 8); z += __shfl_xor(z, 16);
    pL[t] = pv;
    if (t == 0) { mzC[cidx * 2] = m; mzC[cidx * 2 + 1] = z; }
  }
  __syncthreads();
  if (jhalf == 0) {
    float wp = 0.f;
#pragma unroll
    for (int r = 0; r < 16; ++r) {
      const int row = (r & 3) + 8 * (r >> 2) + 4 * jslot;
      const int off = (gb * NN + i0 + row) * 128 + h * 32 + i;
      wp += pL[row] * G[off];
    }
    wp += __shfl_xor(wp, 32);
    if (jslot == 0) wsumC[cidx * 128 + h * 32 + i] = wp;
  }
}

// ---------------------------------------------------------------------------
// K5: combine 64 chunk partials per side (exact softmax merge) + LED head
// ---------------------------------------------------------------------------
__global__ __launch_bounds__(256) void k5_led(const float* __restrict__ e,
                                              const float* __restrict__ wsumC,
                                              const float* __restrict__ mzC,
                                              const float* __restrict__ convW,
                                              const float* __restrict__ convb,
                                              const float* __restrict__ ledW1,
                                              const float* __restrict__ ledb1,
                                              const float* __restrict__ ledW2,
                                              const float* __restrict__ ledb2,
                                              float* __restrict__ out) {
  __shared__ float eaL[256], ebL[256], uL[512], xL[128], lgL[2];
  const int t = threadIdx.x;
  const int wave = t >> 6, lane = t & 63;
  const int bt = blockIdx.x;
  const int gba = bt, gbb = 4 + bt;
  if (t < 128) {
    eaL[t] = e[gba * 256 + t];
    ebL[t] = e[gbb * 256 + t];
    float ma = -1e30f, mb2 = -1e30f;
    for (int c = 0; c < 64; ++c) {
      ma = fmaxf(ma, mzC[(gba * 64 + c) * 2]);
      mb2 = fmaxf(mb2, mzC[(gbb * 64 + c) * 2]);
    }
    float Za = 0.f, Zb = 0.f, sa = 0.f, sb = 0.f;
    for (int c = 0; c < 64; ++c) {
      const float wa = __expf(mzC[(gba * 64 + c) * 2] - ma);
      const float wb = __expf(mzC[(gbb * 64 + c) * 2] - mb2);
      Za += mzC[(gba * 64 + c) * 2 + 1] * wa;
      Zb += mzC[(gbb * 64 + c) * 2 + 1] * wb;
      sa += wsumC[(gba * 64 + c) * 128 + t] * wa;
      sb += wsumC[(gbb * 64 + c) * 128 + t] * wb;
    }
    eaL[128 + t] = sa / Za;
    ebL[128 + t] = sb / Zb;
  }
  __syncthreads();
  uL[256 + t] = eaL[t] - ebL[t];
  const float4 ea4 = *(const float4*)&eaL[lane * 4];
  const float4 eb4 = *(const float4*)&ebL[lane * 4];
  for (int p = 0; p < 32; ++p) {
    const int o0 = p * 8 + wave * 2;
    const float4 w0 = *(const float4*)&convW[o0 * 256 + lane * 4];
    const float4 w1 = *(const float4*)&convW[(o0 + 1) * 256 + lane * 4];
    float sa0 = dot4(w0, ea4), sb0 = dot4(w0, eb4);
    float sa1 = dot4(w1, ea4), sb1 = dot4(w1, eb4);
#pragma unroll
    for (int s = 1; s < 64; s <<= 1) {
      sa0 += __shfl_xor(sa0, s); sb0 += __shfl_xor(sb0, s);
      sa1 += __shfl_xor(sa1, s); sb1 += __shfl_xor(sb1, s);
    }
    if (lane == 0) {
      const float c0 = convb[o0], c1 = convb[o0 + 1];
      uL[o0] = fmaxf(sa0 + c0, sb0 + c0);
      uL[o0 + 1] = fmaxf(sa1 + c1, sb1 + c1);
    }
  }
  __syncthreads();
  for (int p = 0; p < 16; ++p) {
    const int o0 = p * 8 + wave * 2;
    const float* w0 = &ledW1[o0 * 512 + lane * 8];
    const float* w1 = &ledW1[(o0 + 1) * 512 + lane * 8];
    const float4 u0 = *(const float4*)&uL[lane * 8];
    const float4 u1 = *(const float4*)&uL[lane * 8 + 4];
    float s0 = dot4(*(const float4*)&w0[0], u0) + dot4(*(const float4*)&w0[4], u1);
    float s1v = dot4(*(const float4*)&w1[0], u0) + dot4(*(const float4*)&w1[4], u1);
#pragma unroll
    for (int s = 1; s < 64; s <<= 1) { s0 += __shfl_xor(s0, s); s1v += __shfl_xor(s1v, s); }
    if (lane == 0) {
      xL[o0] = fmaxf(s0 + ledb1[o0], 0.f);
      xL[o0 + 1] = fmaxf(s1v + ledb1[o0 + 1], 0.f);
    }
  }
  __syncthreads();
  if (wave < 2) {
    const float2 w = *(const float2*)&ledW2[wave * 128 + lane * 2];
    const float2 xv = *(const float2*)&xL[lane * 2];
    float s0 = w.x * xv.x + w.y * xv.y;
#pragma unroll
    for (int s = 1; s < 64; s <<= 1) s0 += __shfl_xor(s0, s);
    if (lane == 0) lgL[wave] = s0 + ledb2[wave];
  }
  __syncthreads();
  if (t == 0) {
    const float l0 = lgL[0], l1 = lgL[1];
    const float m = fmaxf(l0, l1);
    const float za = __expf(l0 - m) + __expf(l1 - m);
    const float lz = __logf(za);
    out[bt * 2 + 0] = l0 - m - lz;
    out[bt * 2 + 1] = l1 - m - lz;
  }
}

// ---------------------------------------------------------------------------
extern "C" void kernel_launch(void* const* d_in, const int* in_sizes, int n_in,
                              void* d_out, int out_size, void* d_ws, size_t ws_size,
                              hipStream_t stream) {
  (void)in_sizes; (void)n_in; (void)out_size; (void)ws_size;
  const float* a     = (const float*)d_in[0];
  const float* bioA  = (const float*)d_in[1];
  const int*   A     = (const int*)d_in[2];
  const float* b     = (const float*)d_in[3];
  const float* bioB  = (const float*)d_in[4];
  const int*   B     = (const int*)d_in[5];
  const float* initW = (const float*)d_in[6];
  const float* initb = (const float*)d_in[7];
  const float* projW = (const float*)d_in[8];
  const float* attw  = (const float*)d_in[9];
  const float* attb  = (const float*)d_in[10];
  const float* ggeW1 = (const float*)d_in[11];
  const float* ggeb1 = (const float*)d_in[12];
  const float* ggeW2 = (const float*)d_in[13];
  const float* ggeb2 = (const float*)d_in[14];
  const float* convW = (const float*)d_in[15];
  const float* convb = (const float*)d_in[16];
  const float* ledW1 = (const float*)d_in[17];
  const float* ledb1 = (const float*)d_in[18];
  const float* ledW2 = (const float*)d_in[19];
  const float* ledb2 = (const float*)d_in[20];

  float* ws = (float*)d_ws;
  float*          x     = ws;                              // 2,097,152
  unsigned short* xhT2  = (unsigned short*)(ws + 2097152); // 1,048,576 f32-equiv
  float*          s1    = ws + 3145728;                    // 65,536
  float*          s2    = ws + 3211264;                    // 65,536
  float*          G     = ws + 3276800;                    // 2,097,152
  float*          mzC   = ws + 5373952;                    // 1,024
  float*          wsumC = ws + 5374976;                    // 65,536
  float*          hv    = ws + 5440512;                    // 1,024
  float*          e     = ws + 5441536;                    // 2,048
  unsigned int*   adjP  = (unsigned int*)(ws + 5443584);   // 1,048,576 words
  float* out = (float*)d_out;

  k12_fused<<<2056, 256, 0, stream>>>(bioA, bioB, initW, initb, projW, attw,
                                      a, b, ggeW1, ggeb1, ggeW2, ggeb2,
                                      A, B, adjP,
                                      x, xhT2, s1, s2, hv, e);
  k3_attn<<<512, 512, 0, stream>>>(xhT2, s1, s2, adjP, attb, x, hv, G,
                                   wsumC, mzC);
  k5_led<<<4, 256, 0, stream>>>(e, wsumC, mzC, convW, convb, ledW1, ledb1,
                                ledW2, ledb2, out);
}

// Round 20
// 164.856 us; speedup vs baseline: 1.1928x; 1.1928x over previous
//
#include <hip/hip_runtime.h>
#include <hip/hip_bf16.h>
#include <math.h>

#define NN 2048
#define NEG 0.2f
#define LOG2E 1.44269504f

typedef short bf16x8 __attribute__((ext_vector_type(8)));
typedef float f32x16 __attribute__((ext_vector_type(16)));

__device__ __forceinline__ float dot4(float4 a, float4 b) {
  return a.x * b.x + a.y * b.y + a.z * b.z + a.w * b.w;
}

__device__ __forceinline__ unsigned short bfbits(float f) {
  union { __hip_bfloat16 b; unsigned short u; } c;
  c.b = __float2bfloat16(f);
  return c.u;
}

// ---------------------------------------------------------------------------
// K12: fused  x = bio @ initW^T + initb  (phase 1, K=256)
//             y = x @ projW^T -> xhT2 bf16 tile-major + s1/s2  (phase 2)
// Blocks 512..519 instead run the (independent) GGE MLP -> hv, e[0:128].
// ---------------------------------------------------------------------------
__global__ __launch_bounds__(256) void k12_fused(const float* __restrict__ bioA,
                                                 const float* __restrict__ bioB,
                                                 const float* __restrict__ initW,
                                                 const float* __restrict__ initb,
                                                 const float* __restrict__ projW,
                                                 const float* __restrict__ attw,
                                                 const float* __restrict__ a_in,
                                                 const float* __restrict__ b_in,
                                                 const float* __restrict__ ggeW1,
                                                 const float* __restrict__ ggeb1,
                                                 const float* __restrict__ ggeW2,
                                                 const float* __restrict__ ggeb2,
                                                 float* __restrict__ xout,
                                                 unsigned short* __restrict__ xhT2,
                                                 float* __restrict__ s1,
                                                 float* __restrict__ s2,
                                                 float* __restrict__ hvbuf,
                                                 float* __restrict__ e) {
  __shared__ float As[32][36];
  __shared__ float Ws[32][132];
  __shared__ float xT[128][36];
  const int t = threadIdx.x;
  const int wave = t >> 6, lane = t & 63;

  if (blockIdx.x >= 512) {
    // ----- GGE branch (old k4h), 8 blocks -----
    float* inL = (float*)As;          // 512 floats
    float* h1L = ((float*)As) + 512;  // 128 floats (As has 1152)
    const int bb2 = (int)blockIdx.x - 512;
    const int g = bb2 >> 2, b = bb2 & 3;
    const int gb2 = g * 4 + b;
    const float* inp = (g ? b_in : a_in) + b * 512;
    if (t < 128) *(float4*)&inL[t * 4] = *(const float4*)&inp[t * 4];
    __syncthreads();
    for (int p = 0; p < 16; ++p) {
      const int o0 = p * 8 + wave * 2;
      const float* w0 = &ggeW1[o0 * 512 + lane * 8];
      const float* w1 = &ggeW1[(o0 + 1) * 512 + lane * 8];
      const float4 i0v = *(const float4*)&inL[lane * 8];
      const float4 i1v = *(const float4*)&inL[lane * 8 + 4];
      float s0 = dot4(*(const float4*)&w0[0], i0v) + dot4(*(const float4*)&w0[4], i1v);
      float s1v = dot4(*(const float4*)&w1[0], i0v) + dot4(*(const float4*)&w1[4], i1v);
#pragma unroll
      for (int s = 1; s < 64; s <<= 1) { s0 += __shfl_xor(s0, s); s1v += __shfl_xor(s1v, s); }
      if (lane == 0) {
        h1L[o0] = fmaxf(s0 + ggeb1[o0], 0.f);
        h1L[o0 + 1] = fmaxf(s1v + ggeb1[o0 + 1], 0.f);
      }
    }
    __syncthreads();
    for (int p = 0; p < 16; ++p) {
      const int o0 = p * 8 + wave * 2;
      const float2 w0 = *(const float2*)&ggeW2[o0 * 128 + lane * 2];
      const float2 w1 = *(const float2*)&ggeW2[(o0 + 1) * 128 + lane * 2];
      const float2 hvv = *(const float2*)&h1L[lane * 2];
      float s0 = w0.x * hvv.x + w0.y * hvv.y;
      float s1v = w1.x * hvv.x + w1.y * hvv.y;
#pragma unroll
      for (int s = 1; s < 64; s <<= 1) { s0 += __shfl_xor(s0, s); s1v += __shfl_xor(s1v, s); }
      if (lane == 0) {
        const float v0 = fmaxf(s0 + ggeb2[o0], 0.f);
        const float v1 = fmaxf(s1v + ggeb2[o0 + 1], 0.f);
        hvbuf[gb2 * 128 + o0] = v0;
        hvbuf[gb2 * 128 + o0 + 1] = v1;
        e[gb2 * 256 + o0] = v0;
        e[gb2 * 256 + o0 + 1] = v1;
      }
    }
    return;
  }

  // ----- GEMM branch -----
  const int m0 = blockIdx.x * 32;
  const float* A = (m0 < 8192) ? bioA : bioB;
  const int arow0 = (m0 < 8192) ? m0 : (m0 - 8192);
  const int og = t & 31, ig = t >> 5;

  float acc[4][4] = {};
  for (int kt = 0; kt < 256; kt += 32) {
    __syncthreads();
    {
      const int r = t >> 3, kq = t & 7;
      const float4 v = *(const float4*)&A[(arow0 + r) * 256 + kt + kq * 4];
      As[kq * 4 + 0][r] = v.x; As[kq * 4 + 1][r] = v.y;
      As[kq * 4 + 2][r] = v.z; As[kq * 4 + 3][r] = v.w;
    }
#pragma unroll
    for (int u = 0; u < 4; ++u) {
      const int f = u * 256 + t;
      const int o = f >> 3, kq = f & 7;
      const float4 v = *(const float4*)&initW[o * 256 + kt + kq * 4];
      Ws[kq * 4 + 0][o] = v.x; Ws[kq * 4 + 1][o] = v.y;
      Ws[kq * 4 + 2][o] = v.z; Ws[kq * 4 + 3][o] = v.w;
    }
    __syncthreads();
#pragma unroll
    for (int kk = 0; kk < 32; ++kk) {
      const float4 a4 = *(const float4*)&As[kk][ig * 4];
      const float4 w4 = *(const float4*)&Ws[kk][og * 4];
      const float av[4] = {a4.x, a4.y, a4.z, a4.w};
      const float wv[4] = {w4.x, w4.y, w4.z, w4.w};
#pragma unroll
      for (int ii = 0; ii < 4; ++ii)
#pragma unroll
        for (int jj = 0; jj < 4; ++jj) acc[ii][jj] += av[ii] * wv[jj];
    }
  }
  {
    const float4 b4 = *(const float4*)&initb[og * 4];
    const float bj[4] = {b4.x, b4.y, b4.z, b4.w};
#pragma unroll
    for (int ii = 0; ii < 4; ++ii) {
      const int row = m0 + ig * 4 + ii;
      float4 o4;
      o4.x = acc[ii][0] + bj[0]; o4.y = acc[ii][1] + bj[1];
      o4.z = acc[ii][2] + bj[2]; o4.w = acc[ii][3] + bj[3];
      *(float4*)&xout[row * 128 + og * 4] = o4;
    }
#pragma unroll
    for (int jj = 0; jj < 4; ++jj) {
      float4 v;
      v.x = acc[0][jj] + bj[jj]; v.y = acc[1][jj] + bj[jj];
      v.z = acc[2][jj] + bj[jj]; v.w = acc[3][jj] + bj[jj];
      *(float4*)&xT[og * 4 + jj][ig * 4] = v;
    }
  }
  __syncthreads();

  float acc2[4][4] = {};
  for (int kt = 0; kt < 128; kt += 32) {
    __syncthreads();
#pragma unroll
    for (int u = 0; u < 4; ++u) {
      const int f = u * 256 + t;
      const int o = f >> 3, kq = f & 7;
      const float4 v = *(const float4*)&projW[o * 128 + kt + kq * 4];
      Ws[kq * 4 + 0][o] = v.x; Ws[kq * 4 + 1][o] = v.y;
      Ws[kq * 4 + 2][o] = v.z; Ws[kq * 4 + 3][o] = v.w;
    }
    __syncthreads();
#pragma unroll
    for (int kk = 0; kk < 32; ++kk) {
      const float4 a4 = *(const float4*)&xT[kt + kk][ig * 4];
      const float4 w4 = *(const float4*)&Ws[kk][og * 4];
      const float av[4] = {a4.x, a4.y, a4.z, a4.w};
      const float wv[4] = {w4.x, w4.y, w4.z, w4.w};
#pragma unroll
      for (int ii = 0; ii < 4; ++ii)
#pragma unroll
        for (int jj = 0; jj < 4; ++jj) acc2[ii][jj] += av[ii] * wv[jj];
    }
  }
  const int h = og >> 3;
  const int k4i = (og & 7) * 4;
  const int g = m0 >> 13;
  const int bb = (m0 >> 11) & 3;
  const int gb = g * 4 + bb;
  const int n0 = (m0 & 2047) + ig * 4;
  const float4 w1 = *(const float4*)&attw[h * 64 + k4i];
  const float4 w2 = *(const float4*)&attw[h * 64 + 32 + k4i];
  float p1[4], p2[4];
#pragma unroll
  for (int ii = 0; ii < 4; ++ii) {
    float4 v;
    v.x = acc2[ii][0]; v.y = acc2[ii][1]; v.z = acc2[ii][2]; v.w = acc2[ii][3];
    p1[ii] = dot4(v, w1);
    p2[ii] = dot4(v, w2);
  }
  {
    const int mtile = n0 >> 4, jslot = (n0 >> 3) & 1, j8 = n0 & 7;
    const int base2 = ((((gb * 4 + h) * 128 + mtile) * 2 + jslot) * 32) * 8 + j8;
#pragma unroll
    for (int jj = 0; jj < 4; ++jj) {
      const int kin = k4i + jj;
      ushort4 u;
      u.x = bfbits(acc2[0][jj]); u.y = bfbits(acc2[1][jj]);
      u.z = bfbits(acc2[2][jj]); u.w = bfbits(acc2[3][jj]);
      *(ushort4*)&xhT2[base2 + kin * 8] = u;
    }
  }
#pragma unroll
  for (int s = 1; s < 8; s <<= 1) {
#pragma unroll
    for (int ii = 0; ii < 4; ++ii) {
      p1[ii] += __shfl_xor(p1[ii], s);
      p2[ii] += __shfl_xor(p2[ii], s);
    }
  }
  if ((og & 7) == 0) {
#pragma unroll
    for (int ii = 0; ii < 4; ++ii) {
      s1[(gb * 4 + h) * NN + n0 + ii] = p1[ii];
      s2[(gb * 4 + h) * NN + n0 + ii] = p2[ii];
    }
  }
}

// shared prologue body (s2 staging + deep-batched NON-TEMPORAL adjacency)
#define K3_PROLOGUE                                                           \
  {                                                                           \
    const float* s2g = s2w + gb * 4 * NN;                                     \
    _Pragma("unroll")                                                         \
    for (int u = 0; u < 4; ++u) {                                             \
      const int idx = u * 2048 + t * 4;                                       \
      float4 v = *(const float4*)&s2g[idx];                                   \
      v.x *= LOG2E; v.y *= LOG2E; v.z *= LOG2E; v.w *= LOG2E;                 \
      *(float4*)&s2L[idx] = v;                                                \
    }                                                                         \
  }                                                                           \
  _Pragma("unroll")                                                           \
  for (int r4 = 0; r4 < 4; ++r4) {                                            \
    const int r = wave * 4 + r4;                                              \
    const int* arow = adj + r * NN;                                           \
    int av[32];                                                               \
    _Pragma("unroll")                                                         \
    for (int w = 0; w < 32; ++w) av[w] = __builtin_nontemporal_load(&arow[w * 64 + lane]); \
    _Pragma("unroll")                                                         \
    for (int w = 0; w < 32; ++w) {                                            \
      const unsigned long long mm = __ballot(av[w] > 0);                      \
      if (lane < 2) adjL[r * 66 + 2 * w + lane] = (unsigned int)(mm >> (32 * lane)); \
    }                                                                         \
  }

#define K3_SCORE_BODY(MM)                                                     \
    const int j0 = jlo + 16 * (MM) + jslot * 8;                               \
    const unsigned int wbits = adjL[i * 66 + ((jlo + 16 * (MM)) >> 5)];       \
    const unsigned int bits8 = wbits >> ((((MM) & 1) * 16) + jslot * 8);      \
    const float4 s2a = *(const float4*)&s2L[h * 2048 + j0];                   \
    const float4 s2b = *(const float4*)&s2L[h * 2048 + j0 + 4];               \
    const float sv[8] = {s2a.x, s2a.y, s2a.z, s2a.w,                          \
                         s2b.x, s2b.y, s2b.z, s2b.w};                         \
    union { bf16x8 v; unsigned short u[8]; } af;                              \
    float dsum = 0.f;                                                         \
    _Pragma("unroll")                                                         \
    for (int e = 0; e < 8; ++e) {                                             \
      float s = sc1v + sv[e];                                                 \
      s = fmaxf(s, NEG * s);                                                  \
      float pe = __builtin_amdgcn_exp2f(s);                                   \
      pe = ((bits8 >> e) & 1u) ? pe : 0.f;                                    \
      af.u[e] = bfbits(pe);                                                   \
      dsum += pe;                                                             \
    }                                                                         \
    den += dsum;

// ---------------------------------------------------------------------------
// K3: main loop (16-frag ring). Epilogue emits 32-row chunk GAGA softmax
// partials (m_c, z_c, w_c[128]) using hv.
// ---------------------------------------------------------------------------
__global__ __launch_bounds__(512) void k3_attn(const unsigned short* __restrict__ xhT2,
                                               const float* __restrict__ s1w,
                                               const float* __restrict__ s2w,
                                               const int* __restrict__ adjA,
                                               const int* __restrict__ adjB,
                                               const float* __restrict__ attb,
                                               const float* __restrict__ x,
                                               const float* __restrict__ hv,
                                               float* __restrict__ G,
                                               float* __restrict__ wsumC,
                                               float* __restrict__ mzC) {
  __shared__ __align__(16) unsigned char smem3[42240];
  unsigned int* adjL = (unsigned int*)smem3;
  float* s2L = (float*)(smem3 + 8448);
  float* denR = (float*)(smem3 + 41216);
  float* accR = (float*)smem3;
  float* lgW = (float*)(smem3 + 16640);   // [4][32]
  float* pL = (float*)(smem3 + 17280);    // [32]

  const int t = threadIdx.x;
  const int wave = t >> 6, lane = t & 63;
  const int p = (int)blockIdx.x;
  const int blk = (p & 7) * 64 + (p >> 3);
  const int g = blk >> 8, b = (blk >> 6) & 3;
  const int i0 = (blk & 63) * 32;
  const int gb = g * 4 + b;
  const int cidx = gb * 64 + (blk & 63);
  const int* adj = (g ? adjB : adjA) + (b * NN + i0) * NN;
  K3_PROLOGUE
  __syncthreads();

  const int h = wave & 3;
  const int jhalf = wave >> 2;
  const int jlo = jhalf * 1024;
  const int i = lane & 31;
  const int jslot = lane >> 5;
  const float sc1v = (s1w[(gb * 4 + h) * NN + i0 + i] + attb[h]) * LOG2E;
  const unsigned short* bbase = xhT2 + (gb * 4 + h) * 65536 + jhalf * 32768 + lane * 8;
  f32x16 acc = {0.f, 0.f, 0.f, 0.f, 0.f, 0.f, 0.f, 0.f,
                0.f, 0.f, 0.f, 0.f, 0.f, 0.f, 0.f, 0.f};
  float den = 0.f;

#define K3_CSTEP(RB, MM)                                                      \
  {                                                                           \
    K3_SCORE_BODY(MM)                                                         \
    acc = __builtin_amdgcn_mfma_f32_32x32x16_bf16(af.v, RB, acc, 0, 0, 0);    \
  }

  bf16x8 fa0 = *(const bf16x8*)&bbase[0 * 512];
  bf16x8 fa1 = *(const bf16x8*)&bbase[1 * 512];
  bf16x8 fa2 = *(const bf16x8*)&bbase[2 * 512];
  bf16x8 fa3 = *(const bf16x8*)&bbase[3 * 512];
  bf16x8 fb0 = *(const bf16x8*)&bbase[4 * 512];
  bf16x8 fb1 = *(const bf16x8*)&bbase[5 * 512];
  bf16x8 fb2 = *(const bf16x8*)&bbase[6 * 512];
  bf16x8 fb3 = *(const bf16x8*)&bbase[7 * 512];
  bf16x8 fc0 = *(const bf16x8*)&bbase[8 * 512];
  bf16x8 fc1 = *(const bf16x8*)&bbase[9 * 512];
  bf16x8 fc2 = *(const bf16x8*)&bbase[10 * 512];
  bf16x8 fc3 = *(const bf16x8*)&bbase[11 * 512];
  bf16x8 fd0 = *(const bf16x8*)&bbase[12 * 512];
  bf16x8 fd1 = *(const bf16x8*)&bbase[13 * 512];
  bf16x8 fd2 = *(const bf16x8*)&bbase[14 * 512];
  bf16x8 fd3 = *(const bf16x8*)&bbase[15 * 512];
  __builtin_amdgcn_sched_barrier(0);
  for (int mb = 0; mb < 64; mb += 16) {
    K3_CSTEP(fa0, mb + 0)
    K3_CSTEP(fa1, mb + 1)
    K3_CSTEP(fa2, mb + 2)
    K3_CSTEP(fa3, mb + 3)
    __builtin_amdgcn_sched_barrier(0);
    if (mb < 48) {
      fa0 = *(const bf16x8*)&bbase[(mb + 16) * 512];
      fa1 = *(const bf16x8*)&bbase[(mb + 17) * 512];
      fa2 = *(const bf16x8*)&bbase[(mb + 18) * 512];
      fa3 = *(const bf16x8*)&bbase[(mb + 19) * 512];
    }
    __builtin_amdgcn_sched_barrier(0);
    K3_CSTEP(fb0, mb + 4)
    K3_CSTEP(fb1, mb + 5)
    K3_CSTEP(fb2, mb + 6)
    K3_CSTEP(fb3, mb + 7)
    __builtin_amdgcn_sched_barrier(0);
    if (mb < 48) {
      fb0 = *(const bf16x8*)&bbase[(mb + 20) * 512];
      fb1 = *(const bf16x8*)&bbase[(mb + 21) * 512];
      fb2 = *(const bf16x8*)&bbase[(mb + 22) * 512];
      fb3 = *(const bf16x8*)&bbase[(mb + 23) * 512];
    }
    __builtin_amdgcn_sched_barrier(0);
    K3_CSTEP(fc0, mb + 8)
    K3_CSTEP(fc1, mb + 9)
    K3_CSTEP(fc2, mb + 10)
    K3_CSTEP(fc3, mb + 11)
    __builtin_amdgcn_sched_barrier(0);
    if (mb < 48) {
      fc0 = *(const bf16x8*)&bbase[(mb + 24) * 512];
      fc1 = *(const bf16x8*)&bbase[(mb + 25) * 512];
      fc2 = *(const bf16x8*)&bbase[(mb + 26) * 512];
      fc3 = *(const bf16x8*)&bbase[(mb + 27) * 512];
    }
    __builtin_amdgcn_sched_barrier(0);
    K3_CSTEP(fd0, mb + 12)
    K3_CSTEP(fd1, mb + 13)
    K3_CSTEP(fd2, mb + 14)
    K3_CSTEP(fd3, mb + 15)
    __builtin_amdgcn_sched_barrier(0);
    if (mb < 48) {
      fd0 = *(const bf16x8*)&bbase[(mb + 28) * 512];
      fd1 = *(const bf16x8*)&bbase[(mb + 29) * 512];
      fd2 = *(const bf16x8*)&bbase[(mb + 30) * 512];
      fd3 = *(const bf16x8*)&bbase[(mb + 31) * 512];
    }
    __builtin_amdgcn_sched_barrier(0);
  }
#undef K3_CSTEP

  den += __shfl_xor(den, 32);
  if (lane < 32) denR[(h * 2 + jhalf) * 32 + lane] = den;
  __syncthreads();
  if (jhalf == 1) {
#pragma unroll
    for (int r = 0; r < 16; ++r) accR[(h * 16 + r) * 65 + lane] = acc[r];
  }
  __syncthreads();
  const float hvv = hv[gb * 128 + h * 32 + i];
  if (jhalf == 0) {
#pragma unroll
    for (int r = 0; r < 16; ++r) {
      const int row = (r & 3) + 8 * (r >> 2) + 4 * jslot;
      const float dinv = 1.f / (denR[(h * 2 + 0) * 32 + row] + denR[(h * 2 + 1) * 32 + row]);
      const int off = (gb * NN + i0 + row) * 128 + h * 32 + i;
      const float av2 = acc[r] + accR[(h * 16 + r) * 65 + lane];
      const float gval = fmaxf(av2 * dinv, 0.f) + x[off];
      G[off] = gval;
      float c = gval * hvv;
      c += __shfl_xor(c, 1); c += __shfl_xor(c, 2); c += __shfl_xor(c, 4);
      c += __shfl_xor(c, 8); c += __shfl_xor(c, 16);
      if (i == 0) lgW[h * 32 + row] = c;
    }
  }
  __syncthreads();
  if (t < 32) {
    float lg = lgW[t] + lgW[32 + t] + lgW[64 + t] + lgW[96 + t];
    float m = lg;
    m = fmaxf(m, __shfl_xor(m, 1)); m = fmaxf(m, __shfl_xor(m, 2));
    m = fmaxf(m, __shfl_xor(m, 4)); m = fmaxf(m, __shfl_xor(m, 8));
    m = fmaxf(m, __shfl_xor(m, 16));
    const float pv = __expf(lg - m);
    float z = pv;
    z += __shfl_xor(z, 1); z += __shfl_xor(z, 2); z += __shfl_xor(z, 4);
    z += __shfl_xor(z, 8); z += __shfl_xor(z, 16);
    pL[t] = pv;
    if (t == 0) { mzC[cidx * 2] = m; mzC[cidx * 2 + 1] = z; }
  }
  __syncthreads();
  if (jhalf == 0) {
    float wp = 0.f;
#pragma unroll
    for (int r = 0; r < 16; ++r) {
      const int row = (r & 3) + 8 * (r >> 2) + 4 * jslot;
      const int off = (gb * NN + i0 + row) * 128 + h * 32 + i;
      wp += pL[row] * G[off];
    }
    wp += __shfl_xor(wp, 32);
    if (jslot == 0) wsumC[cidx * 128 + h * 32 + i] = wp;
  }
}

// ---------------------------------------------------------------------------
// K5: combine 64 chunk partials per side (exact softmax merge) + LED head
// ---------------------------------------------------------------------------
__global__ __launch_bounds__(256) void k5_led(const float* __restrict__ e,
                                              const float* __restrict__ wsumC,
                                              const float* __restrict__ mzC,
                                              const float* __restrict__ convW,
                                              const float* __restrict__ convb,
                                              const float* __restrict__ ledW1,
                                              const float* __restrict__ ledb1,
                                              const float* __restrict__ ledW2,
                                              const float* __restrict__ ledb2,
                                              float* __restrict__ out) {
  __shared__ float eaL[256], ebL[256], uL[512], xL[128], lgL[2];
  const int t = threadIdx.x;
  const int wave = t >> 6, lane = t & 63;
  const int bt = blockIdx.x;
  const int gba = bt, gbb = 4 + bt;
  if (t < 128) {
    eaL[t] = e[gba * 256 + t];
    ebL[t] = e[gbb * 256 + t];
    float ma = -1e30f, mb2 = -1e30f;
    for (int c = 0; c < 64; ++c) {
      ma = fmaxf(ma, mzC[(gba * 64 + c) * 2]);
      mb2 = fmaxf(mb2, mzC[(gbb * 64 + c) * 2]);
    }
    float Za = 0.f, Zb = 0.f, sa = 0.f, sb = 0.f;
    for (int c = 0; c < 64; ++c) {
      const float wa = __expf(mzC[(gba * 64 + c) * 2] - ma);
      const float wb = __expf(mzC[(gbb * 64 + c) * 2] - mb2);
      Za += mzC[(gba * 64 + c) * 2 + 1] * wa;
      Zb += mzC[(gbb * 64 + c) * 2 + 1] * wb;
      sa += wsumC[(gba * 64 + c) * 128 + t] * wa;
      sb += wsumC[(gbb * 64 + c) * 128 + t] * wb;
    }
    eaL[128 + t] = sa / Za;
    ebL[128 + t] = sb / Zb;
  }
  __syncthreads();
  uL[256 + t] = eaL[t] - ebL[t];
  const float4 ea4 = *(const float4*)&eaL[lane * 4];
  const float4 eb4 = *(const float4*)&ebL[lane * 4];
  for (int p = 0; p < 32; ++p) {
    const int o0 = p * 8 + wave * 2;
    const float4 w0 = *(const float4*)&convW[o0 * 256 + lane * 4];
    const float4 w1 = *(const float4*)&convW[(o0 + 1) * 256 + lane * 4];
    float sa0 = dot4(w0, ea4), sb0 = dot4(w0, eb4);
    float sa1 = dot4(w1, ea4), sb1 = dot4(w1, eb4);
#pragma unroll
    for (int s = 1; s < 64; s <<= 1) {
      sa0 += __shfl_xor(sa0, s); sb0 += __shfl_xor(sb0, s);
      sa1 += __shfl_xor(sa1, s); sb1 += __shfl_xor(sb1, s);
    }
    if (lane == 0) {
      const float c0 = convb[o0], c1 = convb[o0 + 1];
      uL[o0] = fmaxf(sa0 + c0, sb0 + c0);
      uL[o0 + 1] = fmaxf(sa1 + c1, sb1 + c1);
    }
  }
  __syncthreads();
  for (int p = 0; p < 16; ++p) {
    const int o0 = p * 8 + wave * 2;
    const float* w0 = &ledW1[o0 * 512 + lane * 8];
    const float* w1 = &ledW1[(o0 + 1) * 512 + lane * 8];
    const float4 u0 = *(const float4*)&uL[lane * 8];
    const float4 u1 = *(const float4*)&uL[lane * 8 + 4];
    float s0 = dot4(*(const float4*)&w0[0], u0) + dot4(*(const float4*)&w0[4], u1);
    float s1v = dot4(*(const float4*)&w1[0], u0) + dot4(*(const float4*)&w1[4], u1);
#pragma unroll
    for (int s = 1; s < 64; s <<= 1) { s0 += __shfl_xor(s0, s); s1v += __shfl_xor(s1v, s); }
    if (lane == 0) {
      xL[o0] = fmaxf(s0 + ledb1[o0], 0.f);
      xL[o0 + 1] = fmaxf(s1v + ledb1[o0 + 1], 0.f);
    }
  }
  __syncthreads();
  if (wave < 2) {
    const float2 w = *(const float2*)&ledW2[wave * 128 + lane * 2];
    const float2 xv = *(const float2*)&xL[lane * 2];
    float s0 = w.x * xv.x + w.y * xv.y;
#pragma unroll
    for (int s = 1; s < 64; s <<= 1) s0 += __shfl_xor(s0, s);
    if (lane == 0) lgL[wave] = s0 + ledb2[wave];
  }
  __syncthreads();
  if (t == 0) {
    const float l0 = lgL[0], l1 = lgL[1];
    const float m = fmaxf(l0, l1);
    const float za = __expf(l0 - m) + __expf(l1 - m);
    const float lz = __logf(za);
    out[bt * 2 + 0] = l0 - m - lz;
    out[bt * 2 + 1] = l1 - m - lz;
  }
}

// ---------------------------------------------------------------------------
extern "C" void kernel_launch(void* const* d_in, const int* in_sizes, int n_in,
                              void* d_out, int out_size, void* d_ws, size_t ws_size,
                              hipStream_t stream) {
  (void)in_sizes; (void)n_in; (void)out_size; (void)ws_size;
  const float* a     = (const float*)d_in[0];
  const float* bioA  = (const float*)d_in[1];
  const int*   A     = (const int*)d_in[2];
  const float* b     = (const float*)d_in[3];
  const float* bioB  = (const float*)d_in[4];
  const int*   B     = (const int*)d_in[5];
  const float* initW = (const float*)d_in[6];
  const float* initb = (const float*)d_in[7];
  const float* projW = (const float*)d_in[8];
  const float* attw  = (const float*)d_in[9];
  const float* attb  = (const float*)d_in[10];
  const float* ggeW1 = (const float*)d_in[11];
  const float* ggeb1 = (const float*)d_in[12];
  const float* ggeW2 = (const float*)d_in[13];
  const float* ggeb2 = (const float*)d_in[14];
  const float* convW = (const float*)d_in[15];
  const float* convb = (const float*)d_in[16];
  const float* ledW1 = (const float*)d_in[17];
  const float* ledb1 = (const float*)d_in[18];
  const float* ledW2 = (const float*)d_in[19];
  const float* ledb2 = (const float*)d_in[20];

  float* ws = (float*)d_ws;
  float*          x     = ws;                              // 2,097,152
  unsigned short* xhT2  = (unsigned short*)(ws + 2097152); // 1,048,576 f32-equiv
  float*          s1    = ws + 3145728;                    // 65,536
  float*          s2    = ws + 3211264;                    // 65,536
  float*          G     = ws + 3276800;                    // 2,097,152
  float*          mzC   = ws + 5373952;                    // [8][64][2] = 1024
  float*          wsumC = ws + 5374976;                    // [8][64][128] = 65536
  float*          hv    = ws + 5440512;                    // 1,024
  float*          e     = ws + 5441536;                    // 2,048
  float* out = (float*)d_out;

  k12_fused<<<520, 256, 0, stream>>>(bioA, bioB, initW, initb, projW, attw,
                                     a, b, ggeW1, ggeb1, ggeW2, ggeb2,
                                     x, xhT2, s1, s2, hv, e);
  k3_attn<<<512, 512, 0, stream>>>(xhT2, s1, s2, A, B, attb, x, hv, G,
                                   wsumC, mzC);
  k5_led<<<4, 256, 0, stream>>>(e, wsumC, mzC, convW, convb, ledW1, ledb1,
                                ledW2, ledb2, out);
}